// Round 1
// baseline (772.563 us; speedup 1.0000x reference)
//
#include <hip/hip_runtime.h>
#include <hip/hip_bf16.h>

typedef float  f32x4  __attribute__((ext_vector_type(4)));
typedef __bf16 bf16x8 __attribute__((ext_vector_type(8)));
typedef __bf16 bf16x4 __attribute__((ext_vector_type(4)));

#define N_TOK 8192
#define D_DIM 4096
#define O_DIM 4096
#define ER    128
#define KCAT  4224   // D_DIM + ER

// async global->LDS, 16B per lane. LDS dest must be lane-linear (wave base + lane*16).
__device__ __forceinline__ void gl_lds16(const void* g, void* l) {
  __builtin_amdgcn_global_load_lds(
      (const __attribute__((address_space(1))) void*)g,
      (__attribute__((address_space(3))) void*)l, 16, 0, 0);
}

// ---------------- k1: weight prep (fp32 -> bf16, layout fusion) ----------------
// Wcat[o][k]: k<4096 -> W_base[o][k]; k>=4096 -> B_w[e][o][r] with er=k-4096.
// A2[er][d] = A_w flat (E,R,D is contiguous [128][4096]).
__global__ __launch_bounds__(256) void prep_kernel(
    const float* __restrict__ Wb, const float* __restrict__ Bw,
    const float* __restrict__ Aw,
    __bf16* __restrict__ Wcat, __bf16* __restrict__ A2)
{
  size_t i = (size_t)blockIdx.x * 256 + threadIdx.x;
  const size_t WCAT_ELEMS = (size_t)O_DIM * KCAT;  // 17,301,504
  if (i < WCAT_ELEMS) {
    size_t o = i / KCAT;
    int k = (int)(i - o * KCAT);
    float v;
    if (k < D_DIM) {
      v = Wb[o * (size_t)D_DIM + k];
    } else {
      int er = k - D_DIM;              // 0..127
      int e = er >> 4, r = er & 15;
      v = Bw[((size_t)e * O_DIM + o) * 16 + r];
    }
    Wcat[i] = (__bf16)v;
  } else {
    size_t j = i - WCAT_ELEMS;
    if (j < (size_t)ER * D_DIM) A2[j] = (__bf16)Aw[j];
  }
}

// ---------------- k2: gates (fp32) + softmax/threshold/weights + x->bf16 ----------------
__global__ __launch_bounds__(256) void gate_kernel(
    const float* __restrict__ x,
    const float* __restrict__ Wg,    // [8][4096]
    const float* __restrict__ Wthr,  // [4096]
    const float* __restrict__ bthr,  // [1]
    float* __restrict__ wbuf,        // [N][8]
    __bf16* __restrict__ xcat)       // [N][KCAT]
{
  const int n = blockIdx.x;
  const int tid = threadIdx.x;
  const int lane = tid & 63, wave = tid >> 6;
  const f32x4* xr = (const f32x4*)(x + (size_t)n * D_DIM);
  __bf16* xc = xcat + (size_t)n * KCAT;

  float acc[9] = {0,0,0,0,0,0,0,0,0};
#pragma unroll
  for (int it = 0; it < 4; ++it) {
    int c = tid + it * 256;                  // float4 index 0..1023
    f32x4 xv = xr[c];
    bf16x4 bv = { (__bf16)xv[0], (__bf16)xv[1], (__bf16)xv[2], (__bf16)xv[3] };
    *(bf16x4*)(xc + c * 4) = bv;
#pragma unroll
    for (int e = 0; e < 8; ++e) {
      f32x4 wv = *(const f32x4*)(Wg + (size_t)e * D_DIM + c * 4);
      acc[e] += xv[0]*wv[0] + xv[1]*wv[1] + xv[2]*wv[2] + xv[3]*wv[3];
    }
    f32x4 tv = *(const f32x4*)(Wthr + c * 4);
    acc[8] += xv[0]*tv[0] + xv[1]*tv[1] + xv[2]*tv[2] + xv[3]*tv[3];
  }

  __shared__ float red[4][9];
#pragma unroll
  for (int e = 0; e < 9; ++e) {
    float v = acc[e];
    v += __shfl_down(v, 32);
    v += __shfl_down(v, 16);
    v += __shfl_down(v, 8);
    v += __shfl_down(v, 4);
    v += __shfl_down(v, 2);
    v += __shfl_down(v, 1);
    if (lane == 0) red[wave][e] = v;
  }
  __syncthreads();
  if (tid == 0) {
    float g[9];
#pragma unroll
    for (int e = 0; e < 9; ++e) g[e] = red[0][e] + red[1][e] + red[2][e] + red[3][e];
    float m = g[0];
#pragma unroll
    for (int e = 1; e < 8; ++e) m = fmaxf(m, g[e]);
    float p[8], s = 0.f;
#pragma unroll
    for (int e = 0; e < 8; ++e) { p[e] = expf(g[e] - m); s += p[e]; }
    float thr = 0.125f / (1.f + expf(-(g[8] + bthr[0])));
    float ws = 0.f;
#pragma unroll
    for (int e = 0; e < 8; ++e) {
      float a = p[e] / s - thr;
      a = (a >= 0.f) ? a : 0.f;
      p[e] = a; ws += a;
    }
    if (ws == 0.f) ws = 1.f;
    float inv = 1.f / ws;
#pragma unroll
    for (int e = 0; e < 8; ++e) wbuf[(size_t)n * 8 + e] = p[e] * inv;
  }
}

// ---------------- k3: h = x@A2^T (bf16 MFMA), epilogue applies w*2 -> xcat tail ----------------
__global__ __launch_bounds__(256) void gemm_h(
    const __bf16* __restrict__ A,    // xcat (reads cols 0..4095)
    const __bf16* __restrict__ Bm,   // A2 [128][4096]
    const float* __restrict__ wbuf,  // [N][8]
    __bf16* __restrict__ xcat_w)     // xcat (writes cols 4096..4223)
{
  __shared__ __bf16 As[128 * 64];
  __shared__ __bf16 Bs[128 * 64];
  const int tid  = threadIdx.x;
  const int lane = tid & 63;
  const int wave = tid >> 6;
  const int wm = wave >> 1, wn = wave & 1;
  const int quad = lane >> 4, m16 = lane & 15;
  const int bm = blockIdx.x;   // 0..63

  f32x4 acc[4][4] = {};

  for (int k0 = 0; k0 < D_DIM; k0 += 64) {
#pragma unroll
    for (int i = 0; i < 4; ++i) {
      int c = i * 256 + tid;
      int row = c >> 3;
      int ckpos = c & 7;
      int gk = ckpos ^ (row & 7);          // XOR swizzle: keeps coalescing, kills bank conflicts
      gl_lds16(A  + (size_t)(bm * 128 + row) * KCAT  + k0 + gk * 8, As + c * 8);
      gl_lds16(Bm + (size_t)row * D_DIM              + k0 + gk * 8, Bs + c * 8);
    }
    __syncthreads();
#pragma unroll
    for (int kk = 0; kk < 64; kk += 32) {
      bf16x8 af[4], bfr[4];
#pragma unroll
      for (int i = 0; i < 4; ++i) {
        int rr = wm * 64 + i * 16 + m16;
        int ck = (kk >> 3) + quad;
        af[i] = *(const bf16x8*)(As + rr * 64 + ((ck ^ (rr & 7)) * 8));
      }
#pragma unroll
      for (int j = 0; j < 4; ++j) {
        int rr = wn * 64 + j * 16 + m16;
        int ck = (kk >> 3) + quad;
        bfr[j] = *(const bf16x8*)(Bs + rr * 64 + ((ck ^ (rr & 7)) * 8));
      }
#pragma unroll
      for (int i = 0; i < 4; ++i)
#pragma unroll
        for (int j = 0; j < 4; ++j)
          acc[i][j] = __builtin_amdgcn_mfma_f32_16x16x32_bf16(af[i], bfr[j], acc[i][j], 0, 0, 0);
    }
    __syncthreads();
  }

#pragma unroll
  for (int j = 0; j < 4; ++j) {
    int col = wn * 64 + j * 16 + m16;      // er 0..127
    int e = col >> 4;
#pragma unroll
    for (int i = 0; i < 4; ++i) {
      int row0 = bm * 128 + wm * 64 + i * 16 + quad * 4;
#pragma unroll
      for (int r = 0; r < 4; ++r) {
        int row = row0 + r;
        float wv = wbuf[(size_t)row * 8 + e] * 2.0f;   // fold SCALING here
        xcat_w[(size_t)row * KCAT + D_DIM + col] = (__bf16)(acc[i][j][r] * wv);
      }
    }
  }
}

// ---------------- k4: out = xcat @ Wcat^T + bias  (K = 4224 folds base + moe) ----------------
__global__ __launch_bounds__(256) void gemm_main(
    const __bf16* __restrict__ A,    // xcat [N][KCAT]
    const __bf16* __restrict__ Bm,   // Wcat [O][KCAT]
    const float* __restrict__ bias,  // [O]
    float* __restrict__ out)         // [N][O]
{
  __shared__ __bf16 As[128 * 64];
  __shared__ __bf16 Bs[128 * 64];
  const int tid  = threadIdx.x;
  const int lane = tid & 63;
  const int wave = tid >> 6;
  const int wm = wave >> 1, wn = wave & 1;
  const int quad = lane >> 4, m16 = lane & 15;
  const int bm = blockIdx.x;   // 0..63  token tiles
  const int bn = blockIdx.y;   // 0..31  o tiles

  f32x4 acc[4][4] = {};

  for (int k0 = 0; k0 < KCAT; k0 += 64) {
#pragma unroll
    for (int i = 0; i < 4; ++i) {
      int c = i * 256 + tid;
      int row = c >> 3;
      int ckpos = c & 7;
      int gk = ckpos ^ (row & 7);
      gl_lds16(A  + (size_t)(bm * 128 + row) * KCAT + k0 + gk * 8, As + c * 8);
      gl_lds16(Bm + (size_t)(bn * 128 + row) * KCAT + k0 + gk * 8, Bs + c * 8);
    }
    __syncthreads();
#pragma unroll
    for (int kk = 0; kk < 64; kk += 32) {
      bf16x8 af[4], bfr[4];
#pragma unroll
      for (int i = 0; i < 4; ++i) {
        int rr = wm * 64 + i * 16 + m16;
        int ck = (kk >> 3) + quad;
        af[i] = *(const bf16x8*)(As + rr * 64 + ((ck ^ (rr & 7)) * 8));
      }
#pragma unroll
      for (int j = 0; j < 4; ++j) {
        int rr = wn * 64 + j * 16 + m16;
        int ck = (kk >> 3) + quad;
        bfr[j] = *(const bf16x8*)(Bs + rr * 64 + ((ck ^ (rr & 7)) * 8));
      }
#pragma unroll
      for (int i = 0; i < 4; ++i)
#pragma unroll
        for (int j = 0; j < 4; ++j)
          acc[i][j] = __builtin_amdgcn_mfma_f32_16x16x32_bf16(af[i], bfr[j], acc[i][j], 0, 0, 0);
    }
    __syncthreads();
  }

  // epilogue: C/D layout col=lane&15, row=quad*4+reg  (m89/m91-verified)
#pragma unroll
  for (int j = 0; j < 4; ++j) {
    int col = bn * 128 + wn * 64 + j * 16 + m16;
    float bv = bias[col];
#pragma unroll
    for (int i = 0; i < 4; ++i) {
      int row0 = bm * 128 + wm * 64 + i * 16 + quad * 4;
#pragma unroll
      for (int r = 0; r < 4; ++r) {
        out[(size_t)(row0 + r) * O_DIM + col] = acc[i][j][r] + bv;
      }
    }
  }
}

extern "C" void kernel_launch(void* const* d_in, const int* in_sizes, int n_in,
                              void* d_out, int out_size, void* d_ws, size_t ws_size,
                              hipStream_t stream) {
  const float* x    = (const float*)d_in[0];
  const float* Wb   = (const float*)d_in[1];
  const float* bb   = (const float*)d_in[2];
  const float* Wg   = (const float*)d_in[3];
  const float* Wthr = (const float*)d_in[4];
  const float* bthr = (const float*)d_in[5];
  const float* Aw   = (const float*)d_in[6];
  const float* Bw   = (const float*)d_in[7];
  float* out = (float*)d_out;

  // workspace layout (bytes), all 16B-aligned:
  //   xcat  [8192][4224] bf16 : 69,206,016
  //   Wcat  [4096][4224] bf16 : 34,603,008
  //   A2    [ 128][4096] bf16 :  1,048,576
  //   wbuf  [8192][   8] f32  :    262,144   -> total ~105 MB
  char* ws = (char*)d_ws;
  __bf16* xcat = (__bf16*)ws;
  __bf16* Wcat = (__bf16*)(ws + 69206016);
  __bf16* A2   = (__bf16*)(ws + 69206016 + 34603008);
  float*  wbuf = (float*)(ws + 69206016 + 34603008 + 1048576);

  prep_kernel<<<69632, 256, 0, stream>>>(Wb, Bw, Aw, Wcat, A2);
  gate_kernel<<<8192, 256, 0, stream>>>(x, Wg, Wthr, bthr, wbuf, xcat);
  gemm_h<<<64, 256, 0, stream>>>(xcat, A2, wbuf, xcat);
  dim3 grid(64, 32);
  gemm_main<<<grid, 256, 0, stream>>>(xcat, Wcat, bb, out);
}

// Round 2
// 698.933 us; speedup vs baseline: 1.1053x; 1.1053x over previous
//
#include <hip/hip_runtime.h>
#include <hip/hip_bf16.h>

typedef float  f32x4  __attribute__((ext_vector_type(4)));
typedef __bf16 bf16x8 __attribute__((ext_vector_type(8)));
typedef __bf16 bf16x4 __attribute__((ext_vector_type(4)));

#define N_TOK 8192
#define D_DIM 4096
#define O_DIM 4096
#define ER    128
#define KCAT  4224   // D_DIM + ER

// async global->LDS, 16B per lane. LDS dest must be lane-linear (wave base + lane*16).
__device__ __forceinline__ void gl_lds16(const void* g, void* l) {
  __builtin_amdgcn_global_load_lds(
      (const __attribute__((address_space(1))) void*)g,
      (__attribute__((address_space(3))) void*)l, 16, 0, 0);
}

// ---------------- k1: weight prep (fp32 -> bf16, layout fusion) ----------------
__global__ __launch_bounds__(256) void prep_kernel(
    const float* __restrict__ Wb, const float* __restrict__ Bw,
    const float* __restrict__ Aw,
    __bf16* __restrict__ Wcat, __bf16* __restrict__ A2)
{
  size_t i = (size_t)blockIdx.x * 256 + threadIdx.x;
  const size_t WCAT_ELEMS = (size_t)O_DIM * KCAT;  // 17,301,504
  if (i < WCAT_ELEMS) {
    size_t o = i / KCAT;
    int k = (int)(i - o * KCAT);
    float v;
    if (k < D_DIM) {
      v = Wb[o * (size_t)D_DIM + k];
    } else {
      int er = k - D_DIM;              // 0..127
      int e = er >> 4, r = er & 15;
      v = Bw[((size_t)e * O_DIM + o) * 16 + r];
    }
    Wcat[i] = (__bf16)v;
  } else {
    size_t j = i - WCAT_ELEMS;
    if (j < (size_t)ER * D_DIM) A2[j] = (__bf16)Aw[j];
  }
}

// ---------------- k2: gates, 4 tokens per block (amortize Wg loads) ----------------
__global__ __launch_bounds__(256) void gate_kernel(
    const float* __restrict__ x,
    const float* __restrict__ Wg,    // [8][4096]
    const float* __restrict__ Wthr,  // [4096]
    const float* __restrict__ bthr,  // [1]
    float* __restrict__ wbuf,        // [N][8]
    __bf16* __restrict__ xcat)       // [N][KCAT]
{
  const int n0 = blockIdx.x * 4;
  const int tid = threadIdx.x;
  const int lane = tid & 63, wave = tid >> 6;

  float acc[4][9] = {};
#pragma unroll
  for (int it = 0; it < 4; ++it) {
    int c = tid + it * 256;                  // float4 chunk 0..1023
    f32x4 wv[8];
#pragma unroll
    for (int e = 0; e < 8; ++e) wv[e] = *(const f32x4*)(Wg + (size_t)e * D_DIM + c * 4);
    f32x4 tv = *(const f32x4*)(Wthr + c * 4);
#pragma unroll
    for (int t = 0; t < 4; ++t) {
      f32x4 xv = *(const f32x4*)(x + (size_t)(n0 + t) * D_DIM + c * 4);
      bf16x4 bv = { (__bf16)xv[0], (__bf16)xv[1], (__bf16)xv[2], (__bf16)xv[3] };
      *(bf16x4*)(xcat + (size_t)(n0 + t) * KCAT + c * 4) = bv;
#pragma unroll
      for (int e = 0; e < 8; ++e)
        acc[t][e] += xv[0]*wv[e][0] + xv[1]*wv[e][1] + xv[2]*wv[e][2] + xv[3]*wv[e][3];
      acc[t][8] += xv[0]*tv[0] + xv[1]*tv[1] + xv[2]*tv[2] + xv[3]*tv[3];
    }
  }

  __shared__ float red[4][4][9];
#pragma unroll
  for (int t = 0; t < 4; ++t)
#pragma unroll
    for (int e = 0; e < 9; ++e) {
      float v = acc[t][e];
      v += __shfl_down(v, 32);
      v += __shfl_down(v, 16);
      v += __shfl_down(v, 8);
      v += __shfl_down(v, 4);
      v += __shfl_down(v, 2);
      v += __shfl_down(v, 1);
      if (lane == 0) red[wave][t][e] = v;
    }
  __syncthreads();
  if (tid < 4) {
    const int t = tid;
    float g[9];
#pragma unroll
    for (int e = 0; e < 9; ++e)
      g[e] = red[0][t][e] + red[1][t][e] + red[2][t][e] + red[3][t][e];
    float m = g[0];
#pragma unroll
    for (int e = 1; e < 8; ++e) m = fmaxf(m, g[e]);
    float p[8], s = 0.f;
#pragma unroll
    for (int e = 0; e < 8; ++e) { p[e] = expf(g[e] - m); s += p[e]; }
    float thr = 0.125f / (1.f + expf(-(g[8] + bthr[0])));
    float ws = 0.f;
#pragma unroll
    for (int e = 0; e < 8; ++e) {
      float a = p[e] / s - thr;
      a = (a >= 0.f) ? a : 0.f;
      p[e] = a; ws += a;
    }
    if (ws == 0.f) ws = 1.f;
    float inv = 1.f / ws;
#pragma unroll
    for (int e = 0; e < 8; ++e) wbuf[(size_t)(n0 + t) * 8 + e] = p[e] * inv;
  }
}

// ---------------- k3a: h partial GEMM, K split 4 ways (grid 64x4 = 256 blocks) ----------------
__global__ __launch_bounds__(256) void gemm_h_part(
    const __bf16* __restrict__ A,    // xcat (cols 0..4095)
    const __bf16* __restrict__ Bm,   // A2 [128][4096]
    float* __restrict__ pbuf)        // [4][8192][128] fp32 partials
{
  __shared__ __bf16 As[128 * 64];
  __shared__ __bf16 Bs[128 * 64];
  const int tid  = threadIdx.x;
  const int lane = tid & 63;
  const int wave = tid >> 6;
  const int wm = wave >> 1, wn = wave & 1;
  const int quad = lane >> 4, m16 = lane & 15;
  const int bm = blockIdx.x;   // 0..63 token tiles
  const int kc = blockIdx.y;   // 0..3  K chunks of 1024

  f32x4 acc[4][4] = {};

  for (int k0 = kc * 1024; k0 < kc * 1024 + 1024; k0 += 64) {
#pragma unroll
    for (int i = 0; i < 4; ++i) {
      int c = i * 256 + tid;
      int row = c >> 3;
      int gk = (c & 7) ^ (row & 7);
      gl_lds16(A  + (size_t)(bm * 128 + row) * KCAT  + k0 + gk * 8, As + c * 8);
      gl_lds16(Bm + (size_t)row * D_DIM              + k0 + gk * 8, Bs + c * 8);
    }
    __syncthreads();
#pragma unroll
    for (int kk = 0; kk < 64; kk += 32) {
      bf16x8 af[4], bfr[4];
#pragma unroll
      for (int i = 0; i < 4; ++i) {
        int rr = wm * 64 + i * 16 + m16;
        int ck = (kk >> 3) + quad;
        af[i] = *(const bf16x8*)(As + rr * 64 + ((ck ^ (rr & 7)) * 8));
      }
#pragma unroll
      for (int j = 0; j < 4; ++j) {
        int rr = wn * 64 + j * 16 + m16;
        int ck = (kk >> 3) + quad;
        bfr[j] = *(const bf16x8*)(Bs + rr * 64 + ((ck ^ (rr & 7)) * 8));
      }
#pragma unroll
      for (int i = 0; i < 4; ++i)
#pragma unroll
        for (int j = 0; j < 4; ++j)
          acc[i][j] = __builtin_amdgcn_mfma_f32_16x16x32_bf16(af[i], bfr[j], acc[i][j], 0, 0, 0);
    }
    __syncthreads();
  }

#pragma unroll
  for (int j = 0; j < 4; ++j) {
    int col = wn * 64 + j * 16 + m16;
#pragma unroll
    for (int i = 0; i < 4; ++i) {
      int row0 = bm * 128 + wm * 64 + i * 16 + quad * 4;
#pragma unroll
      for (int r = 0; r < 4; ++r)
        pbuf[((size_t)kc * N_TOK + row0 + r) * ER + col] = acc[i][j][r];
    }
  }
}

// ---------------- k3b: combine partials, apply w*2, write bf16 tail ----------------
__global__ __launch_bounds__(256) void combine_kernel(
    const float* __restrict__ pbuf,  // [4][8192][128]
    const float* __restrict__ wbuf,  // [N][8]
    __bf16* __restrict__ xcat)       // writes cols 4096..4223
{
  int id = blockIdx.x * 256 + threadIdx.x;   // 0 .. 8192*128-1
  int row = id >> 7, col = id & 127;
  float s = pbuf[(size_t)row * ER + col]
          + pbuf[((size_t)N_TOK     + row) * ER + col]
          + pbuf[((size_t)N_TOK * 2 + row) * ER + col]
          + pbuf[((size_t)N_TOK * 3 + row) * ER + col];
  float wv = wbuf[(size_t)row * 8 + (col >> 4)] * 2.0f;   // fold SCALING
  xcat[(size_t)row * KCAT + D_DIM + col] = (__bf16)(s * wv);
}

// ---------------- k3-fallback: full-K gemm_h (used only if ws too small for pbuf) ----------------
__global__ __launch_bounds__(256) void gemm_h_full(
    const __bf16* __restrict__ A, const __bf16* __restrict__ Bm,
    const float* __restrict__ wbuf, __bf16* __restrict__ xcat_w)
{
  __shared__ __bf16 As[128 * 64];
  __shared__ __bf16 Bs[128 * 64];
  const int tid  = threadIdx.x;
  const int lane = tid & 63;
  const int wave = tid >> 6;
  const int wm = wave >> 1, wn = wave & 1;
  const int quad = lane >> 4, m16 = lane & 15;
  const int bm = blockIdx.x;

  f32x4 acc[4][4] = {};
  for (int k0 = 0; k0 < D_DIM; k0 += 64) {
#pragma unroll
    for (int i = 0; i < 4; ++i) {
      int c = i * 256 + tid;
      int row = c >> 3;
      int gk = (c & 7) ^ (row & 7);
      gl_lds16(A  + (size_t)(bm * 128 + row) * KCAT  + k0 + gk * 8, As + c * 8);
      gl_lds16(Bm + (size_t)row * D_DIM              + k0 + gk * 8, Bs + c * 8);
    }
    __syncthreads();
#pragma unroll
    for (int kk = 0; kk < 64; kk += 32) {
      bf16x8 af[4], bfr[4];
#pragma unroll
      for (int i = 0; i < 4; ++i) {
        int rr = wm * 64 + i * 16 + m16;
        int ck = (kk >> 3) + quad;
        af[i] = *(const bf16x8*)(As + rr * 64 + ((ck ^ (rr & 7)) * 8));
      }
#pragma unroll
      for (int j = 0; j < 4; ++j) {
        int rr = wn * 64 + j * 16 + m16;
        int ck = (kk >> 3) + quad;
        bfr[j] = *(const bf16x8*)(Bs + rr * 64 + ((ck ^ (rr & 7)) * 8));
      }
#pragma unroll
      for (int i = 0; i < 4; ++i)
#pragma unroll
        for (int j = 0; j < 4; ++j)
          acc[i][j] = __builtin_amdgcn_mfma_f32_16x16x32_bf16(af[i], bfr[j], acc[i][j], 0, 0, 0);
    }
    __syncthreads();
  }
#pragma unroll
  for (int j = 0; j < 4; ++j) {
    int col = wn * 64 + j * 16 + m16;
    int e = col >> 4;
#pragma unroll
    for (int i = 0; i < 4; ++i) {
      int row0 = bm * 128 + wm * 64 + i * 16 + quad * 4;
#pragma unroll
      for (int r = 0; r < 4; ++r) {
        int row = row0 + r;
        float wv = wbuf[(size_t)row * 8 + e] * 2.0f;
        xcat_w[(size_t)row * KCAT + D_DIM + col] = (__bf16)(acc[i][j][r] * wv);
      }
    }
  }
}

// ---------------- k4: out = xcat @ Wcat^T + bias, L2-swizzled grid ----------------
__global__ __launch_bounds__(256) void gemm_main(
    const __bf16* __restrict__ A,    // xcat [N][KCAT]
    const __bf16* __restrict__ Bm,   // Wcat [O][KCAT]
    const float* __restrict__ bias,  // [O]
    float* __restrict__ out)         // [N][O]
{
  __shared__ __bf16 As[128 * 64];
  __shared__ __bf16 Bs[128 * 64];
  const int tid  = threadIdx.x;
  const int lane = tid & 63;
  const int wave = tid >> 6;
  const int wm = wave >> 1, wn = wave & 1;
  const int quad = lane >> 4, m16 = lane & 15;

  // supertile swizzle: concurrent ~512-block window covers 32 bm x 16 bn
  // (A 35MB + B 17MB) instead of 64 bm x 8 bn (A 69MB thrash).
  const int bid = blockIdx.x;          // 0..2047
  const int group = bid >> 10;         // 0..1 (bn halves)
  const int r_ = bid & 1023;
  const int bn = (group << 4) | (r_ & 15);   // 0..31
  const int bm = r_ >> 4;                    // 0..63

  f32x4 acc[4][4] = {};

  for (int k0 = 0; k0 < KCAT; k0 += 64) {
#pragma unroll
    for (int i = 0; i < 4; ++i) {
      int c = i * 256 + tid;
      int row = c >> 3;
      int gk = (c & 7) ^ (row & 7);
      gl_lds16(A  + (size_t)(bm * 128 + row) * KCAT + k0 + gk * 8, As + c * 8);
      gl_lds16(Bm + (size_t)(bn * 128 + row) * KCAT + k0 + gk * 8, Bs + c * 8);
    }
    __syncthreads();
#pragma unroll
    for (int kk = 0; kk < 64; kk += 32) {
      bf16x8 af[4], bfr[4];
#pragma unroll
      for (int i = 0; i < 4; ++i) {
        int rr = wm * 64 + i * 16 + m16;
        int ck = (kk >> 3) + quad;
        af[i] = *(const bf16x8*)(As + rr * 64 + ((ck ^ (rr & 7)) * 8));
      }
#pragma unroll
      for (int j = 0; j < 4; ++j) {
        int rr = wn * 64 + j * 16 + m16;
        int ck = (kk >> 3) + quad;
        bfr[j] = *(const bf16x8*)(Bs + rr * 64 + ((ck ^ (rr & 7)) * 8));
      }
#pragma unroll
      for (int i = 0; i < 4; ++i)
#pragma unroll
        for (int j = 0; j < 4; ++j)
          acc[i][j] = __builtin_amdgcn_mfma_f32_16x16x32_bf16(af[i], bfr[j], acc[i][j], 0, 0, 0);
    }
    __syncthreads();
  }

  // epilogue: C/D layout col=lane&15, row=quad*4+reg (m89/m91-verified)
#pragma unroll
  for (int j = 0; j < 4; ++j) {
    int col = bn * 128 + wn * 64 + j * 16 + m16;
    float bv = bias[col];
#pragma unroll
    for (int i = 0; i < 4; ++i) {
      int row0 = bm * 128 + wm * 64 + i * 16 + quad * 4;
#pragma unroll
      for (int r = 0; r < 4; ++r) {
        out[(size_t)(row0 + r) * O_DIM + col] = acc[i][j][r] + bv;
      }
    }
  }
}

extern "C" void kernel_launch(void* const* d_in, const int* in_sizes, int n_in,
                              void* d_out, int out_size, void* d_ws, size_t ws_size,
                              hipStream_t stream) {
  const float* x    = (const float*)d_in[0];
  const float* Wb   = (const float*)d_in[1];
  const float* bb   = (const float*)d_in[2];
  const float* Wg   = (const float*)d_in[3];
  const float* Wthr = (const float*)d_in[4];
  const float* bthr = (const float*)d_in[5];
  const float* Aw   = (const float*)d_in[6];
  const float* Bw   = (const float*)d_in[7];
  float* out = (float*)d_out;

  // workspace layout (bytes), all 16B-aligned:
  //   xcat [8192][4224] bf16 : 69,206,016
  //   Wcat [4096][4224] bf16 : 34,603,008
  //   A2   [ 128][4096] bf16 :  1,048,576
  //   wbuf [8192][   8] f32  :    262,144     (base = 105,119,744)
  //   pbuf [4][8192][128] f32:  16,777,216    (total = 121,896,960)
  char* ws = (char*)d_ws;
  __bf16* xcat = (__bf16*)ws;
  __bf16* Wcat = (__bf16*)(ws + 69206016);
  __bf16* A2   = (__bf16*)(ws + 69206016 + 34603008);
  float*  wbuf = (float*)(ws + 69206016 + 34603008 + 1048576);
  float*  pbuf = (float*)(ws + 105119744);
  const bool have_pbuf = ws_size >= 121896960;  // constant per deployment -> graph-safe

  prep_kernel<<<69632, 256, 0, stream>>>(Wb, Bw, Aw, Wcat, A2);
  gate_kernel<<<2048, 256, 0, stream>>>(x, Wg, Wthr, bthr, wbuf, xcat);
  if (have_pbuf) {
    dim3 hgrid(64, 4);
    gemm_h_part<<<hgrid, 256, 0, stream>>>(xcat, A2, pbuf);
    combine_kernel<<<4096, 256, 0, stream>>>(pbuf, wbuf, xcat);
  } else {
    gemm_h_full<<<64, 256, 0, stream>>>(xcat, A2, wbuf, xcat);
  }
  gemm_main<<<2048, 256, 0, stream>>>(xcat, Wcat, bb, out);
}

// Round 3
// 652.718 us; speedup vs baseline: 1.1836x; 1.0708x over previous
//
#include <hip/hip_runtime.h>
#include <hip/hip_bf16.h>

typedef float  f32x4  __attribute__((ext_vector_type(4)));
typedef __bf16 bf16x8 __attribute__((ext_vector_type(8)));
typedef __bf16 bf16x4 __attribute__((ext_vector_type(4)));

#define N_TOK 8192
#define D_DIM 4096
#define O_DIM 4096
#define ER    128
#define KCAT  4224   // D_DIM + ER
#define BAUX_ROWS 160  // 128 h + 8 gate + 1 thr + 23 zero pad

// async global->LDS, 16B per lane. LDS dest must be lane-linear (wave base + lane*16).
__device__ __forceinline__ void gl_lds16(const void* g, void* l) {
  __builtin_amdgcn_global_load_lds(
      (const __attribute__((address_space(1))) void*)g,
      (__attribute__((address_space(3))) void*)l, 16, 0, 0);
}

// ---------------- k1: flat convert, shift/mask indexing only ----------------
// chunk = 8 elements. Ranges:
//   [0, 4194304)            x -> xcat[:, 0:4096] bf16        row=id>>9 ch=id&511
//   [4194304, 6291456)      Wb -> Wcat[:, 0:4096]            row=>>9  ch=&511
//   [6291456, 6356992)      Bw -> Wcat[:, 4096:4224]         o=>>4    ch=&15
//   [6356992, 6438912)      Aw/Wg/Wthr/0 -> Baux[160][4096]  row=>>9  ch=&511
__global__ __launch_bounds__(256) void convert_kernel(
    const float* __restrict__ x,  const float* __restrict__ Wb,
    const float* __restrict__ Bw, const float* __restrict__ Aw,
    const float* __restrict__ Wg, const float* __restrict__ Wthr,
    __bf16* __restrict__ xcat, __bf16* __restrict__ Wcat,
    __bf16* __restrict__ Baux)
{
  const int id = blockIdx.x * 256 + threadIdx.x;
  const float* src;
  __bf16* dst;
  if (id < 4194304) {
    int row = id >> 9, ch = id & 511;
    src = x + ((size_t)row << 12) + ch * 8;
    dst = xcat + (size_t)row * KCAT + ch * 8;
  } else if (id < 6291456) {
    int i2 = id - 4194304;
    int row = i2 >> 9, ch = i2 & 511;
    src = Wb + ((size_t)row << 12) + ch * 8;
    dst = Wcat + (size_t)row * KCAT + ch * 8;
  } else if (id < 6356992) {
    int i2 = id - 6291456;
    int o = i2 >> 4, ch = i2 & 15;          // ch: 16 chunks of the 128-wide tail
    int e = ch >> 1, r0 = (ch & 1) * 8;
    src = Bw + (((size_t)e << 12) + o) * 16 + r0;   // 8 contiguous r values
    dst = Wcat + (size_t)o * KCAT + D_DIM + ch * 8;
  } else {
    int i2 = id - 6356992;
    int row = i2 >> 9, ch = i2 & 511;       // row 0..159
    dst = Baux + ((size_t)row << 12) + ch * 8;
    if (row < 128)       src = Aw + ((size_t)row << 12) + ch * 8;
    else if (row < 136)  src = Wg + ((size_t)(row - 128) << 12) + ch * 8;
    else if (row == 136) src = Wthr + ch * 8;
    else {
      bf16x8 z = {};
      *(bf16x8*)dst = z;
      return;
    }
  }
  f32x4 a = *(const f32x4*)src;
  f32x4 b = *(const f32x4*)(src + 4);
  bf16x8 v = { (__bf16)a[0], (__bf16)a[1], (__bf16)a[2], (__bf16)a[3],
               (__bf16)b[0], (__bf16)b[1], (__bf16)b[2], (__bf16)b[3] };
  *(bf16x8*)dst = v;
}

// ---------------- k2: aux GEMM -- h[128] + gate logits[9] in one MFMA pass ----------------
// out pbuf[kc][N][160] fp32 partials; grid (64, KC); K chunk = 4096/KC
__global__ __launch_bounds__(256) void gemm_aux(
    const __bf16* __restrict__ A,    // xcat (cols 0..4095)
    const __bf16* __restrict__ Bm,   // Baux [160][4096]
    float* __restrict__ pbuf, int kchunk)
{
  __shared__ __bf16 As[128 * 64];
  __shared__ __bf16 Bs[BAUX_ROWS * 64];
  const int tid  = threadIdx.x;
  const int lane = tid & 63;
  const int wave = tid >> 6;
  const int wm = wave >> 1, wn = wave & 1;   // wave tile: 64 rows x 80 cols
  const int quad = lane >> 4, m16 = lane & 15;
  const int bm = blockIdx.x;   // 0..63 token tiles
  const int kc = blockIdx.y;

  f32x4 acc[4][5] = {};

  for (int k0 = kc * kchunk; k0 < (kc + 1) * kchunk; k0 += 64) {
#pragma unroll
    for (int i = 0; i < 4; ++i) {
      int c = i * 256 + tid;
      int row = c >> 3;
      int gk = (c & 7) ^ (row & 7);
      gl_lds16(A + (size_t)(bm * 128 + row) * KCAT + k0 + gk * 8, As + c * 8);
    }
#pragma unroll
    for (int i = 0; i < 5; ++i) {
      int c = i * 256 + tid;
      int row = c >> 3;                      // 0..159
      int gk = (c & 7) ^ (row & 7);
      gl_lds16(Bm + ((size_t)row << 12) + k0 + gk * 8, Bs + c * 8);
    }
    __syncthreads();
#pragma unroll
    for (int kk = 0; kk < 64; kk += 32) {
      bf16x8 af[4], bfr[5];
#pragma unroll
      for (int i = 0; i < 4; ++i) {
        int rr = wm * 64 + i * 16 + m16;
        int ck = (kk >> 3) + quad;
        af[i] = *(const bf16x8*)(As + rr * 64 + ((ck ^ (rr & 7)) * 8));
      }
#pragma unroll
      for (int j = 0; j < 5; ++j) {
        int rr = wn * 80 + j * 16 + m16;
        int ck = (kk >> 3) + quad;
        bfr[j] = *(const bf16x8*)(Bs + rr * 64 + ((ck ^ (rr & 7)) * 8));
      }
#pragma unroll
      for (int i = 0; i < 4; ++i)
#pragma unroll
        for (int j = 0; j < 5; ++j)
          acc[i][j] = __builtin_amdgcn_mfma_f32_16x16x32_bf16(af[i], bfr[j], acc[i][j], 0, 0, 0);
    }
    __syncthreads();
  }

#pragma unroll
  for (int j = 0; j < 5; ++j) {
    int col = wn * 80 + j * 16 + m16;
#pragma unroll
    for (int i = 0; i < 4; ++i) {
      int row0 = bm * 128 + wm * 64 + i * 16 + quad * 4;
#pragma unroll
      for (int r = 0; r < 4; ++r)
        pbuf[((size_t)kc * N_TOK + row0 + r) * BAUX_ROWS + col] = acc[i][j][r];
    }
  }
}

// ---------------- k3: combine partials + softmax/threshold + weighted bf16 tail ----------------
// 16 tokens/block, 16 threads/token.
__global__ __launch_bounds__(256) void combine_kernel(
    const float* __restrict__ pbuf,  // [KC][8192][160]
    const float* __restrict__ bthr,
    __bf16* __restrict__ xcat, int KC)
{
  const int tid = threadIdx.x;
  const int tok = tid >> 4, l16 = tid & 15;
  const int row = blockIdx.x * 16 + tok;

  __shared__ float logits[16][9];
  __shared__ float wts[16][8];

  float h[8];
  float lg = 0.f;
#pragma unroll
  for (int i = 0; i < 8; ++i) {
    int c = i * 16 + l16;
    float s = 0.f;
    for (int kc = 0; kc < KC; ++kc)
      s += pbuf[((size_t)kc * N_TOK + row) * BAUX_ROWS + c];
    h[i] = s;
  }
  {
    int c = 128 + l16;
    for (int kc = 0; kc < KC; ++kc)
      lg += pbuf[((size_t)kc * N_TOK + row) * BAUX_ROWS + c];
    if (l16 < 9) logits[tok][l16] = lg;
  }
  __syncthreads();
  if (l16 == 0) {
    float g[9];
#pragma unroll
    for (int e = 0; e < 9; ++e) g[e] = logits[tok][e];
    float m = g[0];
#pragma unroll
    for (int e = 1; e < 8; ++e) m = fmaxf(m, g[e]);
    float p[8], s = 0.f;
#pragma unroll
    for (int e = 0; e < 8; ++e) { p[e] = expf(g[e] - m); s += p[e]; }
    float thr = 0.125f / (1.f + expf(-(g[8] + bthr[0])));
    float ws = 0.f;
#pragma unroll
    for (int e = 0; e < 8; ++e) {
      float a = p[e] / s - thr;
      a = (a >= 0.f) ? a : 0.f;
      p[e] = a; ws += a;
    }
    if (ws == 0.f) ws = 1.f;
    float inv = 2.0f / ws;                    // fold SCALING=2 here
#pragma unroll
    for (int e = 0; e < 8; ++e) wts[tok][e] = p[e] * inv;
  }
  __syncthreads();
#pragma unroll
  for (int i = 0; i < 8; ++i) {
    int c = i * 16 + l16;
    xcat[(size_t)row * KCAT + D_DIM + c] = (__bf16)(h[i] * wts[tok][c >> 4]);
  }
}

// ---------------- k4: out = xcat @ Wcat^T + bias, L2-swizzled grid ----------------
__global__ __launch_bounds__(256) void gemm_main(
    const __bf16* __restrict__ A,    // xcat [N][KCAT]
    const __bf16* __restrict__ Bm,   // Wcat [O][KCAT]
    const float* __restrict__ bias,  // [O]
    float* __restrict__ out)         // [N][O]
{
  __shared__ __bf16 As[128 * 64];
  __shared__ __bf16 Bs[128 * 64];
  const int tid  = threadIdx.x;
  const int lane = tid & 63;
  const int wave = tid >> 6;
  const int wm = wave >> 1, wn = wave & 1;
  const int quad = lane >> 4, m16 = lane & 15;

  const int bid = blockIdx.x;          // 0..2047
  const int group = bid >> 10;         // 0..1 (bn halves)
  const int r_ = bid & 1023;
  const int bn = (group << 4) | (r_ & 15);   // 0..31
  const int bm = r_ >> 4;                    // 0..63

  f32x4 acc[4][4] = {};

  for (int k0 = 0; k0 < KCAT; k0 += 64) {
#pragma unroll
    for (int i = 0; i < 4; ++i) {
      int c = i * 256 + tid;
      int row = c >> 3;
      int gk = (c & 7) ^ (row & 7);
      gl_lds16(A  + (size_t)(bm * 128 + row) * KCAT + k0 + gk * 8, As + c * 8);
      gl_lds16(Bm + (size_t)(bn * 128 + row) * KCAT + k0 + gk * 8, Bs + c * 8);
    }
    __syncthreads();
#pragma unroll
    for (int kk = 0; kk < 64; kk += 32) {
      bf16x8 af[4], bfr[4];
#pragma unroll
      for (int i = 0; i < 4; ++i) {
        int rr = wm * 64 + i * 16 + m16;
        int ck = (kk >> 3) + quad;
        af[i] = *(const bf16x8*)(As + rr * 64 + ((ck ^ (rr & 7)) * 8));
      }
#pragma unroll
      for (int j = 0; j < 4; ++j) {
        int rr = wn * 64 + j * 16 + m16;
        int ck = (kk >> 3) + quad;
        bfr[j] = *(const bf16x8*)(Bs + rr * 64 + ((ck ^ (rr & 7)) * 8));
      }
#pragma unroll
      for (int i = 0; i < 4; ++i)
#pragma unroll
        for (int j = 0; j < 4; ++j)
          acc[i][j] = __builtin_amdgcn_mfma_f32_16x16x32_bf16(af[i], bfr[j], acc[i][j], 0, 0, 0);
    }
    __syncthreads();
  }

  // epilogue: C/D layout col=lane&15, row=quad*4+reg (m89/m91-verified)
#pragma unroll
  for (int j = 0; j < 4; ++j) {
    int col = bn * 128 + wn * 64 + j * 16 + m16;
    float bv = bias[col];
#pragma unroll
    for (int i = 0; i < 4; ++i) {
      int row0 = bm * 128 + wm * 64 + i * 16 + quad * 4;
#pragma unroll
      for (int r = 0; r < 4; ++r) {
        out[(size_t)(row0 + r) * O_DIM + col] = acc[i][j][r] + bv;
      }
    }
  }
}

extern "C" void kernel_launch(void* const* d_in, const int* in_sizes, int n_in,
                              void* d_out, int out_size, void* d_ws, size_t ws_size,
                              hipStream_t stream) {
  const float* x    = (const float*)d_in[0];
  const float* Wb   = (const float*)d_in[1];
  const float* bb   = (const float*)d_in[2];
  const float* Wg   = (const float*)d_in[3];
  const float* Wthr = (const float*)d_in[4];
  const float* bthr = (const float*)d_in[5];
  const float* Aw   = (const float*)d_in[6];
  const float* Bw   = (const float*)d_in[7];
  float* out = (float*)d_out;

  // workspace layout (bytes), all 16B-aligned:
  //   xcat [8192][4224] bf16 : 69,206,016
  //   Wcat [4096][4224] bf16 : 34,603,008
  //   Baux [ 160][4096] bf16 :  1,310,720    (base = 105,119,744)
  //   pbuf [KC][8192][160] f32: KC * 5,242,880
  char* ws = (char*)d_ws;
  __bf16* xcat = (__bf16*)ws;
  __bf16* Wcat = (__bf16*)(ws + 69206016);
  __bf16* Baux = (__bf16*)(ws + 69206016 + 34603008);
  float*  pbuf = (float*)(ws + 105119744);

  // KC chosen from ws_size (constant per deployment -> graph-safe)
  int KC = 1;
  if (ws_size >= 105119744 + 4ull * 5242880) KC = 4;
  else if (ws_size >= 105119744 + 2ull * 5242880) KC = 2;

  convert_kernel<<<25152, 256, 0, stream>>>(x, Wb, Bw, Aw, Wg, Wthr, xcat, Wcat, Baux);
  dim3 agrid(64, KC);
  gemm_aux<<<agrid, 256, 0, stream>>>(xcat, Baux, pbuf, D_DIM / KC);
  combine_kernel<<<512, 256, 0, stream>>>(pbuf, bthr, xcat, KC);
  gemm_main<<<2048, 256, 0, stream>>>(xcat, Wcat, bb, out);
}